// Round 3
// baseline (47.288 us; speedup 1.0000x reference)
//
#include <hip/hip_runtime.h>
#include <stdint.h>

// SNN 50-step integrate-fire spike encoding.
// x: [256,1,4096] f32 -> out: [256,1,4096,50] f32 (0/1 spikes).
// elem = b*4096+f; out[elem*50 + t]. Pure HBM-write-bound (210 MB out).
//
// Phase 1: each thread runs the exact reference f32 recurrence for TWO
//          elements (tid, tid+256), packing the 50 binary spikes of each
//          into a uint64 in LDS (4 KB/block).
// Phase 2: block-cooperative coalesced nontemporal float4 writes of the
//          block's contiguous 512*50-float region: 6400 float4 / 256 thr
//          = exactly 25 iterations, no tail divergence.

#define TIME 50
#define BLOCK 256
#define EPB 512                    // elements per block
#define REGION (EPB * TIME)        // 25600 floats, contiguous
#define NQUADS (REGION / 4)        // 6400 float4s
#define ITERS (NQUADS / BLOCK)     // 25, exact

typedef float f32x4 __attribute__((ext_vector_type(4)));  // true vector type
                                                          // (nontemporal builtin
                                                          // rejects HIP float4)

__global__ __launch_bounds__(BLOCK) void snn_encode_kernel(
    const float* __restrict__ x, float* __restrict__ out, int n_elems) {
    __shared__ unsigned long long sb[EPB];  // 4 KB: spike bitmasks

    const int tid = threadIdx.x;
    const int base = blockIdx.x * EPB;

    // ---- Phase 1: two serial 50-step recurrences (exact ref semantics) ----
    #pragma unroll
    for (int h = 0; h < 2; ++h) {
        const int le = tid + h * BLOCK;
        const int elem = base + le;
        unsigned long long bits = 0ull;
        if (elem < n_elems) {
            const float cur = x[elem] * 1.0f + 1.0f;  // SCALE=1, OFFSET=1
            float v = 0.0f;
            float th = 0.5f;  // THRESH_ENC
            #pragma unroll
            for (int t = 0; t < TIME; ++t) {
                v += cur;                     // integrate (f32 add, as ref)
                if (v >= th) {                // fire
                    v = 0.0f;                 // reset (leak = 1.0)
                    th += 0.03f;              // THRESH_PLUS adaptation
                    bits |= (1ull << t);
                }
            }
        }
        sb[le] = bits;
    }
    __syncthreads();

    // ---- Phase 2: coalesced nontemporal float4 writeout (25 iters exact) --
    float* dst = out + (size_t)blockIdx.x * REGION;
    #pragma unroll 5
    for (int it = 0; it < ITERS; ++it) {
        const int j = (it * BLOCK + tid) * 4;  // float index in region
        f32x4 vals;
        #pragma unroll
        for (int i = 0; i < 4; ++i) {
            const int jj = j + i;
            const int e = jj / TIME;           // magic-mul div by 50
            const int t = jj - e * TIME;
            vals[i] = (float)((sb[e] >> t) & 1ull);
        }
        __builtin_nontemporal_store(vals, reinterpret_cast<f32x4*>(dst + j));
    }
}

extern "C" void kernel_launch(void* const* d_in, const int* in_sizes, int n_in,
                              void* d_out, int out_size, void* d_ws, size_t ws_size,
                              hipStream_t stream) {
    const float* x = (const float*)d_in[0];
    float* out = (float*)d_out;
    const int n = in_sizes[0];               // 256*1*4096 = 1,048,576 elements
    const int blocks = (n + EPB - 1) / EPB;  // 2048
    snn_encode_kernel<<<blocks, BLOCK, 0, stream>>>(x, out, n);
}

// Round 4
// 37.067 us; speedup vs baseline: 1.2757x; 1.2757x over previous
//
#include <hip/hip_runtime.h>
#include <stdint.h>

// SNN 50-step integrate-fire spike encoding.
// x: [256,1,4096] f32 -> out: [256,1,4096,50] f32 (0/1 spikes).
// elem = b*4096+f; out[elem*50 + t]. Pure HBM-write-bound (210 MB out).
//
// Phase 1: each thread runs the exact reference f32 recurrence for TWO
//          elements (tid, tid+256), packing the 50 binary spikes of each
//          into a uint64 in LDS (4 KB/block).
// Phase 2: block-cooperative coalesced float4 writes of the block's
//          contiguous 512*50-float region: 6400 float4 / 256 threads
//          = exactly 25 iterations, no tail divergence.
// NOTE: plain stores, NOT nontemporal — R2 post-mortem: `nt` stores lose
//       L2 write-combining on gfx950 (5.9 -> 4.5 TB/s regression).

#define TIME 50
#define BLOCK 256
#define EPB 512                    // elements per block
#define REGION (EPB * TIME)        // 25600 floats, contiguous
#define NQUADS (REGION / 4)        // 6400 float4s
#define ITERS (NQUADS / BLOCK)     // 25, exact

__global__ __launch_bounds__(BLOCK) void snn_encode_kernel(
    const float* __restrict__ x, float* __restrict__ out, int n_elems) {
    __shared__ unsigned long long sb[EPB];  // 4 KB: spike bitmasks

    const int tid = threadIdx.x;
    const int base = blockIdx.x * EPB;

    // ---- Phase 1: two serial 50-step recurrences (exact ref semantics) ----
    #pragma unroll
    for (int h = 0; h < 2; ++h) {
        const int le = tid + h * BLOCK;
        const int elem = base + le;
        unsigned long long bits = 0ull;
        if (elem < n_elems) {
            const float cur = x[elem] * 1.0f + 1.0f;  // SCALE=1, OFFSET=1
            float v = 0.0f;
            float th = 0.5f;  // THRESH_ENC
            #pragma unroll
            for (int t = 0; t < TIME; ++t) {
                v += cur;                     // integrate (f32 add, as ref)
                if (v >= th) {                // fire
                    v = 0.0f;                 // reset (leak = 1.0)
                    th += 0.03f;              // THRESH_PLUS adaptation
                    bits |= (1ull << t);
                }
            }
        }
        sb[le] = bits;
    }
    __syncthreads();

    // ---- Phase 2: coalesced float4 writeout (25 iters exact) ----
    float* dst = out + (size_t)blockIdx.x * REGION;
    #pragma unroll 5
    for (int it = 0; it < ITERS; ++it) {
        const int j = (it * BLOCK + tid) * 4;  // float index in region
        float vals[4];
        #pragma unroll
        for (int i = 0; i < 4; ++i) {
            const int jj = j + i;
            const int e = jj / TIME;           // magic-mul div by 50
            const int t = jj - e * TIME;
            vals[i] = (float)((sb[e] >> t) & 1ull);
        }
        *reinterpret_cast<float4*>(dst + j) =
            make_float4(vals[0], vals[1], vals[2], vals[3]);
    }
}

extern "C" void kernel_launch(void* const* d_in, const int* in_sizes, int n_in,
                              void* d_out, int out_size, void* d_ws, size_t ws_size,
                              hipStream_t stream) {
    const float* x = (const float*)d_in[0];
    float* out = (float*)d_out;
    const int n = in_sizes[0];               // 256*1*4096 = 1,048,576 elements
    const int blocks = (n + EPB - 1) / EPB;  // 2048
    snn_encode_kernel<<<blocks, BLOCK, 0, stream>>>(x, out, n);
}